// Round 7
// baseline (179.972 us; speedup 1.0000x reference)
//
#include <hip/hip_runtime.h>

// PositionWiseSpatialAttention — fused flash-style, MI355X gfx950.  R7.
//
// R6 post-mortem: dur flat at 117us with MfmaUtil 29 / VALU 33 / HBM 14 /
// occ 27 -> latency-bound, no pipe saturated.  MFMA floor is ~34us; the gap
// is barrier lockstep (2/tile x 32 tiles, only 3 blocks/CU) + dependent MFMA
// chains (12-deep ST, 6-deep O0) + L2-hostile block->XCD mapping.  R7:
//  * double-buffered K/V LDS: staging writes go to the other buffer, ONE
//    __syncthreads per tile (was 2), staging overlaps compute.
//  * chain-broken accumulators: ST = 3 per-split-term partials (4-chains);
//    O = 4 accumulators (O0a hh / O0b lh+hl / O1a / O1b), summed at end.
//  * XCD swizzle: g = bx%96 so XCD = bx%8 = g%8 -> per-XCD x working set
//    12 slabs (3MB, fits 4MB L2) instead of 96 (25MB).
//  * adj loads issued at tile top (~400cyc lead to use).
// Numerics unchanged from R5/R6 (3-term split bf16, exp2 w/ folded scale).

#define NB    8
#define NT    12
#define NNODE 1024
#define ND    64
#define XROW  768   /* NT*ND */

typedef __bf16 bf16x8  __attribute__((ext_vector_type(8)));
typedef __bf16 bf16x2  __attribute__((ext_vector_type(2)));
typedef float  floatx4 __attribute__((ext_vector_type(4)));
typedef float  floatx16 __attribute__((ext_vector_type(16)));
typedef unsigned uintx4 __attribute__((ext_vector_type(4)));

#define MFMA32(a,b,c) __builtin_amdgcn_mfma_f32_32x32x16_bf16((a),(b),(c),0,0,0)
#define QSCALE 0.18033688011112042f   /* 0.125 * log2(e) */

#define KSTRIDE 72    /* bf16 per K row (d-major), 144 B */
#define VSTRIDE 40    /* bf16 per V row (key-major), 80 B */
#define OFF_KHI 0
#define OFF_KLO 4608
#define OFF_VHI 9216
#define OFF_VLO 14336
#define BUFBYTES 19456
#define SMEM_BYTES (2*BUFBYTES)   /* 38912 -> 4 blocks/CU by LDS */

struct bfpair { __bf16 h, l; };

__device__ __forceinline__ bfpair split1(float f) {
    bfpair r;
    __bf16 hb = (__bf16)f;
    float hf = __builtin_bit_cast(float,
                   (unsigned)__builtin_bit_cast(unsigned short, hb) << 16);
    r.h = hb;
    r.l = (__bf16)(f - hf);
    return r;
}

__device__ __forceinline__ unsigned pk2(__bf16 a, __bf16 b) {
    bf16x2 t; t[0] = a; t[1] = b;
    return __builtin_bit_cast(unsigned, t);
}

// Assemble B-frag (k=(lane>>5)*8+j) from C-layout packed pairs via one
// half-wave exchange.  A0,A1 = C-reg group 2kc; B0,B1 = group 2kc+1.
__device__ __forceinline__ bf16x8 xchg(unsigned A0, unsigned A1,
                                       unsigned B0, unsigned B1, int L5) {
    unsigned sA = L5 ? A0 : B0;
    unsigned sB = L5 ? A1 : B1;
    unsigned rA = (unsigned)__shfl_xor((int)sA, 32);
    unsigned rB = (unsigned)__shfl_xor((int)sB, 32);
    uintx4 u;
    u[0] = L5 ? rA : A0;
    u[1] = L5 ? rB : A1;
    u[2] = L5 ? B0 : rA;
    u[3] = L5 ? B1 : rB;
    return __builtin_bit_cast(bf16x8, u);
}

__global__ void __launch_bounds__(256, 2)
spattn(const float* __restrict__ x, const float* __restrict__ adj,
       const float* __restrict__ theta, float* __restrict__ out)
{
    __shared__ __align__(16) char smem[SMEM_BYTES];

    const int tid  = threadIdx.x;
    const int wave = tid >> 6;
    const int lane = tid & 63;
    const int q31  = lane & 31;
    const int L5   = lane >> 5;

    const int bx   = blockIdx.x;
    const int g    = bx % 96;       // XCD swizzle: bx%8 == g%8
    const int rblk = bx / 96;
    const int bb   = g / NT;
    const int tt   = g - bb * NT;
    const int row0 = rblk * 128;
    const int qglob = row0 + wave*32 + q31;

    const float* xbase = x + (size_t)bb * (NNODE * XROW) + tt * ND;

    // ---- Q B-frags (hi/lo), pre-scaled: lane holds Q[qglob][dc*16+L5*8+j] --
    bf16x8 qh[4], ql[4];
    {
        const float* qsrc = xbase + (size_t)qglob * XROW;
        #pragma unroll
        for (int dc = 0; dc < 4; ++dc) {
            floatx4 f0 = *(const floatx4*)(qsrc + dc*16 + L5*8);
            floatx4 f1 = *(const floatx4*)(qsrc + dc*16 + L5*8 + 4);
            #pragma unroll
            for (int i = 0; i < 4; ++i) {
                bfpair p0 = split1(f0[i]*QSCALE);
                qh[dc][i]   = p0.h; ql[dc][i]   = p0.l;
                bfpair p1 = split1(f1[i]*QSCALE);
                qh[dc][4+i] = p1.h; ql[dc][4+i] = p1.l;
            }
        }
    }

    floatx16 O0a = {}, O0b = {}, O1a = {}, O1b = {};
    float lpA = 0.f, lpB = 0.f;

    // staging maps: K[key][d] 1 key x 8 d;  V[d][key] 1 d x 8 keys
    const int skey = tid >> 3;
    const int sd0  = (tid & 7) * 8;
    const int svd  = tid >> 2;
    const int svk0 = (tid & 3) * 8;
    floatx4 kf0, kf1;
    float vf[8];

    // ---- preloop: tile 0 -> buf0; tile 1 -> regs; one barrier ----
    {
        const float* ksrc = xbase + (size_t)skey * XROW + sd0;
        kf0 = *(const floatx4*)ksrc;
        kf1 = *(const floatx4*)(ksrc + 4);
        const float* vsrc = xbase + (size_t)svk0 * XROW + svd;
        #pragma unroll
        for (int i = 0; i < 8; ++i) vf[i] = vsrc[i * XROW];

        bf16x8 h, l;
        #pragma unroll
        for (int i = 0; i < 4; ++i) {
            bfpair p0 = split1(kf0[i]); h[i]   = p0.h; l[i]   = p0.l;
            bfpair p1 = split1(kf1[i]); h[4+i] = p1.h; l[4+i] = p1.l;
        }
        *(bf16x8*)(smem + OFF_KHI + skey*144 + sd0*2) = h;
        *(bf16x8*)(smem + OFF_KLO + skey*144 + sd0*2) = l;
        bf16x8 vh, vl;
        #pragma unroll
        for (int i = 0; i < 8; ++i) {
            bfpair p = split1(vf[i]); vh[i] = p.h; vl[i] = p.l;
        }
        *(bf16x8*)(smem + OFF_VHI + svd*80 + svk0*2) = vh;
        *(bf16x8*)(smem + OFF_VLO + svd*80 + svk0*2) = vl;

        // tile 1 into regs
        const float* ksrc1 = xbase + (size_t)(32 + skey) * XROW + sd0;
        kf0 = *(const floatx4*)ksrc1;
        kf1 = *(const floatx4*)(ksrc1 + 4);
        const float* vsrc1 = xbase + (size_t)(32 + svk0) * XROW + svd;
        #pragma unroll
        for (int i = 0; i < 8; ++i) vf[i] = vsrc1[i * XROW];
    }
    __syncthreads();

    for (int ct = 0; ct < 32; ++ct) {
        const int key0 = ct * 32;
        const char* cur = smem + (ct & 1) * BUFBYTES;
        char* nxt = smem + ((ct + 1) & 1) * BUFBYTES;

        // adj for this lane's query, keys key0 + rg*8 + L5*4 + 0..3
        floatx4 adjv[4];
        #pragma unroll
        for (int rg = 0; rg < 4; ++rg)
            adjv[rg] = *(const floatx4*)(adj + (size_t)qglob * NNODE
                                         + key0 + rg*8 + L5*4);

        // ---- stage tile ct+1 (in regs) into the other buffer ----
        if (ct < 31) {
            bf16x8 h, l;
            #pragma unroll
            for (int i = 0; i < 4; ++i) {
                bfpair p0 = split1(kf0[i]); h[i]   = p0.h; l[i]   = p0.l;
                bfpair p1 = split1(kf1[i]); h[4+i] = p1.h; l[4+i] = p1.l;
            }
            *(bf16x8*)(nxt + OFF_KHI + skey*144 + sd0*2) = h;
            *(bf16x8*)(nxt + OFF_KLO + skey*144 + sd0*2) = l;
            bf16x8 vh, vl;
            #pragma unroll
            for (int i = 0; i < 8; ++i) {
                bfpair p = split1(vf[i]); vh[i] = p.h; vl[i] = p.l;
            }
            *(bf16x8*)(nxt + OFF_VHI + svd*80 + svk0*2) = vh;
            *(bf16x8*)(nxt + OFF_VLO + svd*80 + svk0*2) = vl;
        }
        // ---- prefetch tile ct+2 into regs ----
        if (ct < 30) {
            const int nk = key0 + 64;
            const float* ksrc = xbase + (size_t)(nk + skey) * XROW + sd0;
            kf0 = *(const floatx4*)ksrc;
            kf1 = *(const floatx4*)(ksrc + 4);
            const float* vsrc = xbase + (size_t)(nk + svk0) * XROW + svd;
            #pragma unroll
            for (int i = 0; i < 8; ++i) vf[i] = vsrc[i * XROW];
        }

        // ---- S^T = K.Q^T, 3 per-term partials (4-long chains) ----
        floatx16 STa = {}, STb = {}, STc = {};
        #pragma unroll
        for (int dc = 0; dc < 4; ++dc) {
            bf16x8 kh = *(const bf16x8*)(cur + OFF_KHI + q31*144 + (dc*16 + L5*8)*2);
            bf16x8 kl = *(const bf16x8*)(cur + OFF_KLO + q31*144 + (dc*16 + L5*8)*2);
            STa = MFMA32(kh, qh[dc], STa);
            STb = MFMA32(kl, qh[dc], STb);
            STc = MFMA32(kh, ql[dc], STc);
        }
        // ---- P^T = adj * exp2(S): reg r -> key (r&3)+8*(r>>2)+4*L5 ----
        __bf16 pth[16], ptl[16];
        #pragma unroll
        for (int r = 0; r < 16; ++r) {
            float s = (STa[r] + STb[r]) + STc[r];
            float w = __builtin_amdgcn_exp2f(s);
            if (r & 1) lpB += w; else lpA += w;
            bfpair p = split1(adjv[r >> 2][r & 3] * w);
            pth[r] = p.h; ptl[r] = p.l;
        }
        unsigned GH[4][2], GL[4][2];
        #pragma unroll
        for (int gg = 0; gg < 4; ++gg) {
            GH[gg][0] = pk2(pth[4*gg],   pth[4*gg+1]);
            GH[gg][1] = pk2(pth[4*gg+2], pth[4*gg+3]);
            GL[gg][0] = pk2(ptl[4*gg],   ptl[4*gg+1]);
            GL[gg][1] = pk2(ptl[4*gg+2], ptl[4*gg+3]);
        }
        // ---- O^T += V^T . P^T, 4 independent accumulators ----
        #pragma unroll
        for (int kc = 0; kc < 2; ++kc) {
            bf16x8 bh = xchg(GH[2*kc][0], GH[2*kc][1],
                             GH[2*kc+1][0], GH[2*kc+1][1], L5);
            bf16x8 bl = xchg(GL[2*kc][0], GL[2*kc][1],
                             GL[2*kc+1][0], GL[2*kc+1][1], L5);
            bf16x8 v0h = *(const bf16x8*)(cur + OFF_VHI + q31*80      + (kc*16 + L5*8)*2);
            bf16x8 v0l = *(const bf16x8*)(cur + OFF_VLO + q31*80      + (kc*16 + L5*8)*2);
            bf16x8 v1h = *(const bf16x8*)(cur + OFF_VHI + (32+q31)*80 + (kc*16 + L5*8)*2);
            bf16x8 v1l = *(const bf16x8*)(cur + OFF_VLO + (32+q31)*80 + (kc*16 + L5*8)*2);
            O0a = MFMA32(v0h, bh, O0a);
            O1a = MFMA32(v1h, bh, O1a);
            O0b = MFMA32(v0l, bh, O0b);
            O1b = MFMA32(v1l, bh, O1b);
            O0b = MFMA32(v0h, bl, O0b);
            O1b = MFMA32(v1h, bl, O1b);
        }
        __syncthreads();    // reads of cur done; writes to nxt visible
    }

    // ---- denominator ----
    float lpart = lpA + lpB;
    float l = lpart + __shfl_xor(lpart, 32);
    float linv = 1.0f / l;

    // ---- epilogue (LDS/barrier-free): out^T = theta^T . (O^T*linv), relu --
    bf16x8 th[2][4], tlo[2][4];
    #pragma unroll
    for (int ot = 0; ot < 2; ++ot)
        #pragma unroll
        for (int kc = 0; kc < 4; ++kc)
            #pragma unroll
            for (int j = 0; j < 8; ++j) {
                float tv = theta[(size_t)(kc*16 + L5*8 + j) * ND + ot*32 + q31];
                bfpair p = split1(tv);
                th[ot][kc][j] = p.h; tlo[ot][kc][j] = p.l;
            }

    __bf16 agh[32], agl[32];
    #pragma unroll
    for (int r = 0; r < 16; ++r) {
        bfpair p = split1((O0a[r] + O0b[r]) * linv);
        agh[r] = p.h; agl[r] = p.l;
    }
    #pragma unroll
    for (int r = 0; r < 16; ++r) {
        bfpair p = split1((O1a[r] + O1b[r]) * linv);
        agh[16+r] = p.h; agl[16+r] = p.l;
    }
    unsigned AH[8][2], AL[8][2];
    #pragma unroll
    for (int gg = 0; gg < 8; ++gg) {
        AH[gg][0] = pk2(agh[4*gg],   agh[4*gg+1]);
        AH[gg][1] = pk2(agh[4*gg+2], agh[4*gg+3]);
        AL[gg][0] = pk2(agl[4*gg],   agl[4*gg+1]);
        AL[gg][1] = pk2(agl[4*gg+2], agl[4*gg+3]);
    }

    floatx16 OC0 = {}, OC1 = {};
    #pragma unroll
    for (int kc = 0; kc < 4; ++kc) {
        bf16x8 bh = xchg(AH[2*kc][0], AH[2*kc][1],
                         AH[2*kc+1][0], AH[2*kc+1][1], L5);
        bf16x8 bl = xchg(AL[2*kc][0], AL[2*kc][1],
                         AL[2*kc+1][0], AL[2*kc+1][1], L5);
        OC0 = MFMA32(th[0][kc], bh, OC0);
        OC1 = MFMA32(th[1][kc], bh, OC1);
        OC0 = MFMA32(tlo[0][kc], bh, OC0);
        OC1 = MFMA32(tlo[1][kc], bh, OC1);
        OC0 = MFMA32(th[0][kc], bl, OC0);
        OC1 = MFMA32(th[1][kc], bl, OC1);
    }

    float* obase = out + (size_t)bb * (NNODE * XROW) + tt * ND
                       + (size_t)qglob * XROW;
    #pragma unroll
    for (int rg = 0; rg < 4; ++rg) {
        floatx4 v0, v1;
        #pragma unroll
        for (int i = 0; i < 4; ++i) {
            float a = OC0[4*rg + i]; v0[i] = a > 0.f ? a : 0.f;
            float b = OC1[4*rg + i]; v1[i] = b > 0.f ? b : 0.f;
        }
        *(floatx4*)(obase + 8*rg + 4*L5)      = v0;
        *(floatx4*)(obase + 32 + 8*rg + 4*L5) = v1;
    }
}

extern "C" void kernel_launch(void* const* d_in, const int* in_sizes, int n_in,
                              void* d_out, int out_size, void* d_ws, size_t ws_size,
                              hipStream_t stream) {
    (void)in_sizes; (void)n_in; (void)d_ws; (void)ws_size; (void)out_size;
    const float* x     = (const float*)d_in[0];
    const float* adj   = (const float*)d_in[1];
    const float* theta = (const float*)d_in[2];
    float* out = (float*)d_out;
    spattn<<<dim3(768), dim3(256), 0, stream>>>(x, adj, theta, out);
}